// Round 12
// baseline (95.493 us; speedup 1.0000x reference)
//
#include <hip/hip_runtime.h>
#include <hip/hip_fp16.h>
#include <math.h>

// LDR toep_corner via FFT chain, radix-16 registerized FFT (4096 = 16^3).
// out[j,b] = Re ifft( sum_{i,s} Gf_ijs . fft( D . fft( Hf_ijs . Xf_ib ) ) )
// Hf = fft(D.H), Xf = ifft(conj(D).x), Gf = fft(G), D_k = exp(i*pi*k/N).
//
// R12: pre and fin were latency-bound (grid 256/128 = 1 block/CU = 1 wave/
// SIMD). Two-lane blocks: 512 threads = 2 independent 256-thread FFT lanes,
// own 32KB LDS half each (64KB/block, R3-proven), shared barriers (lanes run
// identical stage sequences). 2 waves/SIMD -> ~2x latency hiding. Fin also
// folds the sh half-spectrum into the FFT LDS buffer (reads fenced before
// stage-A writes). Mid unchanged from R11 (two-for-one real pack, fp16 Ph).
// Fixed cost: ~44us fill of 256MB d_ws + ~4us input restore per timed call.

#define NFFT  4096
#define NT    256
#define CIN   4
#define COUT  4
#define RANK  4
#define BATCH 32
#define PI_F  3.14159265358979323846f

__device__ __forceinline__ float2 cmul(float2 a, float2 b) {
    return make_float2(a.x*b.x - a.y*b.y, a.x*b.y + a.y*b.x);
}
__device__ __forceinline__ float2 cadd(float2 a, float2 b){ return make_float2(a.x+b.x, a.y+b.y); }
__device__ __forceinline__ float2 csub(float2 a, float2 b){ return make_float2(a.x-b.x, a.y-b.y); }

// LDS bank swizzle (R2-proven: SQ_LDS_BANK_CONFLICT ~ 0).
__device__ __forceinline__ int SW(int e){ return e ^ ((e >> 4) & 15); }

// 16-point DFT in registers, natural order in/out (R2-proven numerics).
template<int SIGN>
__device__ __forceinline__ void dft16(float2 v[16]) {
    const float sgn = (float)SIGN;
    const float C8 = 0.923879532511287f, S8 = 0.382683432365090f, H2 = 0.707106781186548f;
    const float2 w1 = make_float2( C8,  sgn*S8);
    const float2 w2 = make_float2( H2,  sgn*H2);
    const float2 w3 = make_float2( S8,  sgn*C8);
    const float2 w4 = make_float2(0.f,  sgn);
    const float2 w6 = make_float2(-H2,  sgn*H2);
    const float2 w9 = make_float2(-C8, -sgn*S8);
    float2 t[16];
    #pragma unroll
    for (int p = 0; p < 4; ++p) {
        float2 a0 = v[p], a1 = v[p+4], a2 = v[p+8], a3 = v[p+12];
        float2 b0 = cadd(a0,a2), b1 = csub(a0,a2), b2 = cadd(a1,a3), b3 = csub(a1,a3);
        float2 ib3 = make_float2(-sgn*b3.y, sgn*b3.x);   // SIGN*i*b3
        float2 X0 = cadd(b0,b2), X2c = csub(b0,b2);
        float2 X1 = cadd(b1,ib3), X3 = csub(b1,ib3);
        if (p == 1) { X1 = cmul(X1,w1); X2c = cmul(X2c,w2); X3 = cmul(X3,w3); }
        else if (p == 2) { X1 = cmul(X1,w2); X2c = cmul(X2c,w4); X3 = cmul(X3,w6); }
        else if (p == 3) { X1 = cmul(X1,w3); X2c = cmul(X2c,w6); X3 = cmul(X3,w9); }
        t[4*p+0]=X0; t[4*p+1]=X1; t[4*p+2]=X2c; t[4*p+3]=X3;
    }
    #pragma unroll
    for (int q = 0; q < 4; ++q) {
        float2 a0 = t[q], a1 = t[q+4], a2 = t[q+8], a3 = t[q+12];
        float2 b0 = cadd(a0,a2), b1 = csub(a0,a2), b2 = cadd(a1,a3), b3 = csub(a1,a3);
        float2 ib3 = make_float2(-sgn*b3.y, sgn*b3.x);
        v[q+0]  = cadd(b0,b2);
        v[q+8]  = csub(b0,b2);
        v[q+4]  = cadd(b1,ib3);
        v[q+12] = csub(b1,ib3);
    }
}

// v[k] *= e^{i*k*ang}; two independent power chains (depth ~8 not 15).
__device__ __forceinline__ void twiddle16(float2 v[16], float ang) {
    float sn, cs; __sincosf(ang, &sn, &cs);
    float2 w  = make_float2(cs, sn);
    float2 w2 = cmul(w, w);
    float2 to = w;   // odd powers
    float2 te = w2;  // even powers
    v[1] = cmul(v[1], to);
    v[2] = cmul(v[2], te);
    #pragma unroll
    for (int k = 3; k < 16; k += 2) {
        to = cmul(to, w2); v[k] = cmul(v[k], to);
        if (k + 1 < 16) { te = cmul(te, w2); v[k+1] = cmul(v[k+1], te); }
    }
}

// Stockham radix-16, 3 stages, single 32KB buffer (R2-proven).
// Input: v[r] = x[ltid + 256r]. Output: v[k] = X[ltid + 256k].
// Barriers are block-wide: in multi-lane blocks all lanes must call in
// lockstep (identical call sequence). Trailing barrier: lds reusable on exit.
template<int SIGN>
__device__ void fft4096_r16(float2 v[16], float2* lds, int ltid) {
    dft16<SIGN>(v);
    twiddle16(v, (float)SIGN * 2.0f * PI_F * (float)ltid / 4096.0f);
    #pragma unroll
    for (int k = 0; k < 16; ++k) lds[SW(16*ltid + k)] = v[k];
    __syncthreads();
    #pragma unroll
    for (int r = 0; r < 16; ++r) v[r] = lds[SW(ltid + 256*r)];
    dft16<SIGN>(v);
    twiddle16(v, (float)SIGN * 2.0f * PI_F * (float)(ltid >> 4) / 256.0f);
    __syncthreads();                       // in-place: all reads before any write
    {
        const int q = ltid & 15, p = ltid >> 4;
        #pragma unroll
        for (int k = 0; k < 16; ++k) lds[SW(q + 256*p + 16*k)] = v[k];
    }
    __syncthreads();
    #pragma unroll
    for (int r = 0; r < 16; ++r) v[r] = lds[SW(ltid + 256*r)];
    dft16<SIGN>(v);
    __syncthreads();                       // lds reusable by caller
}

// ---- Kernel A: precompute. Two-lane blocks: grid 128 x 512 threads.
// task = bid*2 + lane in [0,256): 0..63 Hf rows, 64..127 Gf, 128..255 Xf.
// Type boundaries are even -> branches are block-uniform (barrier-safe).
__global__ __launch_bounds__(512, 2) void ldr_pre_k(
    const float* __restrict__ x, const float* __restrict__ G, const float* __restrict__ H,
    float2* __restrict__ Hf, float2* __restrict__ Gf, float2* __restrict__ Xf)
{
    __shared__ float2 lds2[2][NFFT];     // 64 KB
    const int tid  = threadIdx.x;
    const int lane = tid >> 8;
    const int ltid = tid & 255;
    float2* lds = lds2[lane];
    const int task = blockIdx.x * 2 + lane;
    float2 v[16];
    if (task < 64) {
        const float* h = H + (size_t)task * NFFT;
        float sn, cs; __sincosf(PI_F * (float)ltid / (float)NFFT, &sn, &cs);
        float2 d = make_float2(cs, sn);
        const float2 dstep = make_float2(0.980785280403230449f, 0.195090322016128268f); // e^{i*pi/16}
        #pragma unroll
        for (int k = 0; k < 16; ++k) {
            float hv = h[ltid + 256*k];
            v[k] = make_float2(d.x*hv, d.y*hv);
            d = cmul(d, dstep);
        }
        fft4096_r16<-1>(v, lds, ltid);
        float2* o = Hf + (size_t)task * NFFT;
        #pragma unroll
        for (int k = 0; k < 16; ++k) o[ltid + 256*k] = v[k];
    } else if (task < 128) {
        const int row = task - 64;
        const float* g = G + (size_t)row * NFFT;
        #pragma unroll
        for (int k = 0; k < 16; ++k) v[k] = make_float2(g[ltid + 256*k], 0.0f);
        fft4096_r16<-1>(v, lds, ltid);
        float2* o = Gf + (size_t)row * NFFT;
        #pragma unroll
        for (int k = 0; k < 16; ++k) o[ltid + 256*k] = v[k];
    } else {
        const int row = task - 128;
        const float* xp = x + (size_t)row * NFFT;
        float sn, cs; __sincosf(PI_F * (float)ltid / (float)NFFT, &sn, &cs);
        float2 d = make_float2(cs, -sn);                                                 // conj(D)
        const float2 dstep = make_float2(0.980785280403230449f, -0.195090322016128268f);
        #pragma unroll
        for (int k = 0; k < 16; ++k) {
            float xv = xp[ltid + 256*k];
            v[k] = make_float2(d.x*xv, d.y*xv);
            d = cmul(d, dstep);
        }
        fft4096_r16<1>(v, lds, ltid);
        const float invn = 1.0f / (float)NFFT;
        float2* o = Xf + (size_t)row * NFFT;
        #pragma unroll
        for (int k = 0; k < 16; ++k) o[ltid + 256*k] = make_float2(v[k].x*invn, v[k].y*invn);
    }
}

// ---- Kernel B: middle (unchanged from R11). grid 1024 = (ij*2+pr)(32) x
// b(32); one rank PAIR per wg via two-for-one real pack; two full FFTs, no
// regs live across FFT calls. Lower-half Y as fp16, DC.x/Nyq.x in elem 0.
__global__ __launch_bounds__(NT, 2) void ldr_mid_k(
    const float2* __restrict__ Hf, const float2* __restrict__ Xf,
    const float2* __restrict__ Gf, __half2* __restrict__ Ph)
{
    __shared__ float2 lds[NFFT];
    const int tid = threadIdx.x;
    const int bid = blockIdx.x;
    const int b   = bid & (BATCH - 1);
    const int ip  = bid >> 5;           // ij*2 + pr, [0,32)
    const int pr  = ip & 1;
    const int ij  = ip >> 1;
    const int i   = ij >> 2;            // COUT = 4
    const int j   = ij & 3;
    const int r0  = ij*RANK + 2*pr;     // rows s0 = r0, s1 = r0+1
    const float2* xrow = Xf + (size_t)(i*BATCH + b) * NFFT;
    const float2* h0 = Hf + (size_t)r0 * NFFT;
    const float2* h1 = h0 + NFFT;
    const float2* g0 = Gf + (size_t)r0 * NFFT;
    const float2* g1 = g0 + NFFT;

    float2 v[16];
    #pragma unroll
    for (int k = 0; k < 16; ++k) {
        const int e = tid + 256*k;
        const float2 xv = xrow[e];
        const float2 a  = cmul(h0[e], xv);
        const float2 c  = cmul(h1[e], xv);
        v[k] = make_float2(a.x - c.y, a.y + c.x);
    }
    fft4096_r16<-1>(v, lds, tid);
    {
        float sn, cs; __sincosf(PI_F * (float)tid / (float)NFFT, &sn, &cs);
        float2 d = make_float2(cs, sn);
        const float2 dstep = make_float2(0.980785280403230449f, 0.195090322016128268f);
        #pragma unroll
        for (int k = 0; k < 16; ++k) { v[k] = cmul(v[k], d); d = cmul(d, dstep); }
    }
    fft4096_r16<-1>(v, lds, tid);       // Z = fft(t0) + i*fft(t1); lds free after

    // Stage upper half of Z for mirror access.
    #pragma unroll
    for (int k = 8; k < 16; ++k) lds[SW(tid + 256*k)] = v[k];
    __syncthreads();

    const int u = i*2 + pr;             // plane in [0,8)
    __half2* prow = Ph + (size_t)((u*COUT + j)*BATCH + b) * (NFFT/2);
    #pragma unroll
    for (int k = 0; k < 8; ++k) {
        const int e = tid + 256*k;
        const float2 Zk = v[k];
        float2 Zm;
        if (e == 0) Zm = Zk;
        else        Zm = lds[SW(4096 - e)];
        const float2 V1 = make_float2(0.5f*(Zk.x + Zm.x), 0.5f*(Zk.y - Zm.y));
        const float2 V2 = make_float2(0.5f*(Zk.y + Zm.y), 0.5f*(Zm.x - Zk.x));
        float2 Y = cadd(cmul(g0[e], V1), cmul(g1[e], V2));
        if (k == 0 && tid == 0) {
            const float2 Zn = v[8];
            const float Ynyq = g0[2048].x * Zn.x + g1[2048].x * Zn.y;
            Y = make_float2(Y.x, Ynyq);      // pack DC.x / Nyq.x
        }
        prow[e] = __floats2half2_rn(Y.x, Y.y);
    }
}

// ---- Kernel C: final. Two-lane blocks: grid 64 x 512 threads; out row
// obid = bid*2 + lane. sh lives in the FFT lds buffer (reads fenced before
// stage-A overwrites). Sum 8 fp16 half-rows via int4 loads, conjugate-mirror
// the upper half, one inverse FFT, write Re/N.
__global__ __launch_bounds__(512, 2) void ldr_fin_k(
    const __half2* __restrict__ Ph, float* __restrict__ out)
{
    __shared__ float2 lds2[2][NFFT];     // 64 KB
    const int tid  = threadIdx.x;
    const int lane = tid >> 8;
    const int ltid = tid & 255;
    float2* lds = lds2[lane];
    const int obid = blockIdx.x * 2 + lane;   // j*BATCH + b, [0,128)
    const int b = obid & (BATCH - 1);
    const int j = obid >> 5;

    // Thread accumulates complex positions 4*ltid + r + 1024*c, c<2, r<4.
    float2 a[8];
    #pragma unroll
    for (int k = 0; k < 8; ++k) a[k] = make_float2(0.f, 0.f);
    #pragma unroll
    for (int u = 0; u < 8; ++u) {
        const int4* row4 = (const int4*)(Ph + (size_t)((u*COUT + j)*BATCH + b) * (NFFT/2));
        #pragma unroll
        for (int c = 0; c < 2; ++c) {
            const int4 w = row4[ltid + 256*c];
            const int ww[4] = { w.x, w.y, w.z, w.w };
            #pragma unroll
            for (int r = 0; r < 4; ++r) {
                __half2 h = *(const __half2*)&ww[r];
                float2 f = __half22float2(h);
                a[c*4+r] = cadd(a[c*4+r], f);
            }
        }
    }
    // Publish summed half-spectrum into lds[0..2047] (plain indexing).
    {
        float4* sh4 = (float4*)lds;
        #pragma unroll
        for (int c = 0; c < 2; ++c) {
            sh4[2*(ltid + 256*c) + 0] = make_float4(a[c*4+0].x, a[c*4+0].y, a[c*4+1].x, a[c*4+1].y);
            sh4[2*(ltid + 256*c) + 1] = make_float4(a[c*4+2].x, a[c*4+2].y, a[c*4+3].x, a[c*4+3].y);
        }
    }
    __syncthreads();

    const float dc  = lds[0].x;          // broadcast reads
    const float nyq = lds[0].y;
    float2 v[16];
    #pragma unroll
    for (int k = 0; k < 8; ++k) v[k] = lds[ltid + 256*k];
    if (ltid == 0) v[0] = make_float2(dc, 0.0f);
    #pragma unroll
    for (int k = 8; k < 16; ++k) {
        const int m = 4096 - (ltid + 256*k);         // mirror index in [1,2048]
        if (m == 2048) {                              // only ltid==0, k==8
            v[k] = make_float2(nyq, 0.0f);
        } else {
            float2 c = lds[m];
            v[k] = make_float2(c.x, -c.y);            // conj
        }
    }
    __syncthreads();    // all sh reads complete before FFT overwrites lds
    fft4096_r16<1>(v, lds, ltid);
    const float invn = 1.0f / (float)NFFT;
    float* orow = out + (size_t)obid * NFFT;
    #pragma unroll
    for (int k = 0; k < 16; ++k) orow[ltid + 256*k] = v[k].x * invn;
}

extern "C" void kernel_launch(void* const* d_in, const int* in_sizes, int n_in,
                              void* d_out, int out_size, void* d_ws, size_t ws_size,
                              hipStream_t stream) {
    const float* x = (const float*)d_in[0];   // (CIN, B, N)
    const float* G = (const float*)d_in[1];   // (CIN, COUT, R, N)
    const float* H = (const float*)d_in[2];   // (CIN, COUT, R, N)
    float* out = (float*)d_out;               // (COUT, B, N)

    float2*  Hf = (float2*)d_ws;                    // 64 rows  (2 MB)
    float2*  Gf = Hf + (size_t)64 * NFFT;           // 64 rows  (2 MB)
    float2*  Xf = Gf + (size_t)64 * NFFT;           // 128 rows (4 MB)
    __half2* Ph = (__half2*)(Xf + (size_t)128 * NFFT); // 1024 half-rows x 2048 h2 (8 MB)

    ldr_pre_k<<<128, 512, 0, stream>>>(x, G, H, Hf, Gf, Xf);
    ldr_mid_k<<<CIN * COUT * RANK * BATCH / 2, NT, 0, stream>>>(Hf, Xf, Gf, Ph);
    ldr_fin_k<<<COUT * BATCH / 2, 512, 0, stream>>>(Ph, out);
}

// Round 13
// 90.455 us; speedup vs baseline: 1.0557x; 1.0557x over previous
//
#include <hip/hip_runtime.h>
#include <hip/hip_fp16.h>
#include <math.h>

// LDR toep_corner via FFT chain, radix-16 registerized FFT (4096 = 16^3).
// out[j,b] = Re ifft( sum_{i,s} Gf_ijs . fft( D . fft( Hf_ijs . Xf_ib ) ) )
// Hf = fft(D.H), Xf = ifft(conj(D).x), Gf = fft(G), D_k = exp(i*pi*k/N).
//
// R13 = R11 (proven 91.2us; R12's two-lane blocks halved CU coverage and
// regressed) + H-pair combine: mid's input P = h0.x + i*(h1.x) = (h0+i*h1).x,
// and Hc = fft(D.(h0+i*h1)) = Hf0 + i*Hf1 — pre computes the packed pair row
// directly (one FFT, NO unpack); mid reads ONE h-row instead of two.
// Pre grid 224 = 32 Hc + 64 Gf + 128 Xf. Mid: two-for-one real pack
// (t = D.fft(Hf.Xf) is real), 2 FFTs per rank pair, fp16 half-spectrum Ph.
// Fin: sum 8 planes, conjugate mirror, one ifft. All launch_bounds(256,2)
// (VGPR cap 256 — (256,4) caused catastrophic spill, R4/R5/R9).
// Fixed cost: ~44us harness fill of 256MB d_ws + restore, not controllable.

#define NFFT  4096
#define NT    256
#define CIN   4
#define COUT  4
#define RANK  4
#define BATCH 32
#define PI_F  3.14159265358979323846f

__device__ __forceinline__ float2 cmul(float2 a, float2 b) {
    return make_float2(a.x*b.x - a.y*b.y, a.x*b.y + a.y*b.x);
}
__device__ __forceinline__ float2 cadd(float2 a, float2 b){ return make_float2(a.x+b.x, a.y+b.y); }
__device__ __forceinline__ float2 csub(float2 a, float2 b){ return make_float2(a.x-b.x, a.y-b.y); }

// LDS bank swizzle (R2-proven: SQ_LDS_BANK_CONFLICT ~ 0).
__device__ __forceinline__ int SW(int e){ return e ^ ((e >> 4) & 15); }

// 16-point DFT in registers, natural order in/out (R2-proven numerics).
template<int SIGN>
__device__ __forceinline__ void dft16(float2 v[16]) {
    const float sgn = (float)SIGN;
    const float C8 = 0.923879532511287f, S8 = 0.382683432365090f, H2 = 0.707106781186548f;
    const float2 w1 = make_float2( C8,  sgn*S8);
    const float2 w2 = make_float2( H2,  sgn*H2);
    const float2 w3 = make_float2( S8,  sgn*C8);
    const float2 w4 = make_float2(0.f,  sgn);
    const float2 w6 = make_float2(-H2,  sgn*H2);
    const float2 w9 = make_float2(-C8, -sgn*S8);
    float2 t[16];
    #pragma unroll
    for (int p = 0; p < 4; ++p) {
        float2 a0 = v[p], a1 = v[p+4], a2 = v[p+8], a3 = v[p+12];
        float2 b0 = cadd(a0,a2), b1 = csub(a0,a2), b2 = cadd(a1,a3), b3 = csub(a1,a3);
        float2 ib3 = make_float2(-sgn*b3.y, sgn*b3.x);   // SIGN*i*b3
        float2 X0 = cadd(b0,b2), X2c = csub(b0,b2);
        float2 X1 = cadd(b1,ib3), X3 = csub(b1,ib3);
        if (p == 1) { X1 = cmul(X1,w1); X2c = cmul(X2c,w2); X3 = cmul(X3,w3); }
        else if (p == 2) { X1 = cmul(X1,w2); X2c = cmul(X2c,w4); X3 = cmul(X3,w6); }
        else if (p == 3) { X1 = cmul(X1,w3); X2c = cmul(X2c,w6); X3 = cmul(X3,w9); }
        t[4*p+0]=X0; t[4*p+1]=X1; t[4*p+2]=X2c; t[4*p+3]=X3;
    }
    #pragma unroll
    for (int q = 0; q < 4; ++q) {
        float2 a0 = t[q], a1 = t[q+4], a2 = t[q+8], a3 = t[q+12];
        float2 b0 = cadd(a0,a2), b1 = csub(a0,a2), b2 = cadd(a1,a3), b3 = csub(a1,a3);
        float2 ib3 = make_float2(-sgn*b3.y, sgn*b3.x);
        v[q+0]  = cadd(b0,b2);
        v[q+8]  = csub(b0,b2);
        v[q+4]  = cadd(b1,ib3);
        v[q+12] = csub(b1,ib3);
    }
}

// v[k] *= e^{i*k*ang}; two independent power chains (depth ~8 not 15).
__device__ __forceinline__ void twiddle16(float2 v[16], float ang) {
    float sn, cs; __sincosf(ang, &sn, &cs);
    float2 w  = make_float2(cs, sn);
    float2 w2 = cmul(w, w);
    float2 to = w;   // odd powers
    float2 te = w2;  // even powers
    v[1] = cmul(v[1], to);
    v[2] = cmul(v[2], te);
    #pragma unroll
    for (int k = 3; k < 16; k += 2) {
        to = cmul(to, w2); v[k] = cmul(v[k], to);
        if (k + 1 < 16) { te = cmul(te, w2); v[k+1] = cmul(v[k+1], te); }
    }
}

// Stockham radix-16, 3 stages, single 32KB buffer (R2-proven).
// Input: v[r] = x[tid + 256r]. Output: v[k] = X[tid + 256k].
// Trailing barrier: lds reusable by caller on exit.
template<int SIGN>
__device__ void fft4096_r16(float2 v[16], float2* lds, int tid) {
    dft16<SIGN>(v);
    twiddle16(v, (float)SIGN * 2.0f * PI_F * (float)tid / 4096.0f);
    #pragma unroll
    for (int k = 0; k < 16; ++k) lds[SW(16*tid + k)] = v[k];
    __syncthreads();
    #pragma unroll
    for (int r = 0; r < 16; ++r) v[r] = lds[SW(tid + 256*r)];
    dft16<SIGN>(v);
    twiddle16(v, (float)SIGN * 2.0f * PI_F * (float)(tid >> 4) / 256.0f);
    __syncthreads();                       // in-place: all reads before any write
    {
        const int q = tid & 15, p = tid >> 4;
        #pragma unroll
        for (int k = 0; k < 16; ++k) lds[SW(q + 256*p + 16*k)] = v[k];
    }
    __syncthreads();
    #pragma unroll
    for (int r = 0; r < 16; ++r) v[r] = lds[SW(tid + 256*r)];
    dft16<SIGN>(v);
    __syncthreads();                       // lds reusable by caller
}

// ---- Kernel A: precompute. grid 224 x 256.
// bid 0..31: Hc pair rows (ONE fft of D.(h0 + i*h1), no unpack needed);
// bid 32..95: Gf rows; bid 96..223: Xf rows.
__global__ __launch_bounds__(NT, 2) void ldr_pre_k(
    const float* __restrict__ x, const float* __restrict__ G, const float* __restrict__ H,
    float2* __restrict__ Hc, float2* __restrict__ Gf, float2* __restrict__ Xf)
{
    __shared__ float2 lds[NFFT];
    const int tid = threadIdx.x;
    const int bid = blockIdx.x;
    float2 v[16];
    if (bid < 32) {
        // Hc[p] = fft(D.(H[2p] + i*H[2p+1])) = Hf[2p] + i*Hf[2p+1]
        const float* h0 = H + (size_t)(2*bid)     * NFFT;
        const float* h1 = H + (size_t)(2*bid + 1) * NFFT;
        float sn, cs; __sincosf(PI_F * (float)tid / (float)NFFT, &sn, &cs);
        float2 d = make_float2(cs, sn);
        const float2 dstep = make_float2(0.980785280403230449f, 0.195090322016128268f); // e^{i*pi/16}
        #pragma unroll
        for (int k = 0; k < 16; ++k) {
            const int e = tid + 256*k;
            v[k] = cmul(d, make_float2(h0[e], h1[e]));
            d = cmul(d, dstep);
        }
        fft4096_r16<-1>(v, lds, tid);
        float2* o = Hc + (size_t)bid * NFFT;
        #pragma unroll
        for (int k = 0; k < 16; ++k) o[tid + 256*k] = v[k];
    } else if (bid < 96) {
        const int row = bid - 32;
        const float* g = G + (size_t)row * NFFT;
        #pragma unroll
        for (int k = 0; k < 16; ++k) v[k] = make_float2(g[tid + 256*k], 0.0f);
        fft4096_r16<-1>(v, lds, tid);
        float2* o = Gf + (size_t)row * NFFT;
        #pragma unroll
        for (int k = 0; k < 16; ++k) o[tid + 256*k] = v[k];
    } else {
        const int row = bid - 96;
        const float* xp = x + (size_t)row * NFFT;
        float sn, cs; __sincosf(PI_F * (float)tid / (float)NFFT, &sn, &cs);
        float2 d = make_float2(cs, -sn);                                                 // conj(D)
        const float2 dstep = make_float2(0.980785280403230449f, -0.195090322016128268f);
        #pragma unroll
        for (int k = 0; k < 16; ++k) {
            float xv = xp[tid + 256*k];
            v[k] = make_float2(d.x*xv, d.y*xv);
            d = cmul(d, dstep);
        }
        fft4096_r16<1>(v, lds, tid);
        const float invn = 1.0f / (float)NFFT;
        float2* o = Xf + (size_t)row * NFFT;
        #pragma unroll
        for (int k = 0; k < 16; ++k) o[tid + 256*k] = make_float2(v[k].x*invn, v[k].y*invn);
    }
}

// ---- Kernel B: middle. grid 1024 = (ij*2 + pr)(32) x b(32); one rank PAIR
// per wg. Input P = Hc[ip].Xf (one cmul/elem — Hc is the packed pair). Two
// full FFTs, no regs live across FFT calls (spill-free shape, R7-proven).
// Hermitian unpack of Z = fft(t0)+i*fft(t1) via mirror staged in LDS.
// Lower-half Y as fp16, DC.x / Nyq.x packed into element 0; plane u = ip/... 
// u = i*2 + pr (8 planes), row ((u*COUT + j)*BATCH + b), 2048 half2.
__global__ __launch_bounds__(NT, 2) void ldr_mid_k(
    const float2* __restrict__ Hc, const float2* __restrict__ Xf,
    const float2* __restrict__ Gf, __half2* __restrict__ Ph)
{
    __shared__ float2 lds[NFFT];
    const int tid = threadIdx.x;
    const int bid = blockIdx.x;
    const int b   = bid & (BATCH - 1);
    const int ip  = bid >> 5;           // ij*2 + pr, [0,32)
    const int pr  = ip & 1;
    const int ij  = ip >> 1;
    const int i   = ij >> 2;            // COUT = 4
    const int j   = ij & 3;
    const int r0  = ij*RANK + 2*pr;     // G rows s0 = r0, s1 = r0+1
    const float2* xrow = Xf + (size_t)(i*BATCH + b) * NFFT;
    const float2* hc = Hc + (size_t)ip * NFFT;
    const float2* g0 = Gf + (size_t)r0 * NFFT;
    const float2* g1 = g0 + NFFT;

    float2 v[16];
    #pragma unroll
    for (int k = 0; k < 16; ++k) {
        const int e = tid + 256*k;
        v[k] = cmul(hc[e], xrow[e]);    // = (h0+i*h1).x = h0.x + i*(h1.x)
    }
    fft4096_r16<-1>(v, lds, tid);
    {
        float sn, cs; __sincosf(PI_F * (float)tid / (float)NFFT, &sn, &cs);
        float2 d = make_float2(cs, sn);
        const float2 dstep = make_float2(0.980785280403230449f, 0.195090322016128268f);
        #pragma unroll
        for (int k = 0; k < 16; ++k) { v[k] = cmul(v[k], d); d = cmul(d, dstep); }
    }
    fft4096_r16<-1>(v, lds, tid);       // Z = fft(t0) + i*fft(t1); lds free after

    // Stage upper half of Z for mirror access.
    #pragma unroll
    for (int k = 8; k < 16; ++k) lds[SW(tid + 256*k)] = v[k];
    __syncthreads();

    const int u = i*2 + pr;             // plane in [0,8)
    __half2* prow = Ph + (size_t)((u*COUT + j)*BATCH + b) * (NFFT/2);
    #pragma unroll
    for (int k = 0; k < 8; ++k) {
        const int e = tid + 256*k;
        const float2 Zk = v[k];
        float2 Zm;
        if (e == 0) Zm = Zk;
        else        Zm = lds[SW(4096 - e)];
        const float2 V1 = make_float2(0.5f*(Zk.x + Zm.x), 0.5f*(Zk.y - Zm.y));
        const float2 V2 = make_float2(0.5f*(Zk.y + Zm.y), 0.5f*(Zm.x - Zk.x));
        float2 Y = cadd(cmul(g0[e], V1), cmul(g1[e], V2));
        if (k == 0 && tid == 0) {
            const float2 Zn = v[8];
            const float Ynyq = g0[2048].x * Zn.x + g1[2048].x * Zn.y;
            Y = make_float2(Y.x, Ynyq);      // pack DC.x / Nyq.x
        }
        prow[e] = __floats2half2_rn(Y.x, Y.y);
    }
}

// ---- Kernel C: final (R11 shape). grid 128 = (j,b). Sum 8 fp16 half-rows
// via int4 loads, conjugate-mirror upper half, one inverse FFT, write Re/N.
__global__ __launch_bounds__(NT, 2) void ldr_fin_k(
    const __half2* __restrict__ Ph, float* __restrict__ out)
{
    __shared__ float2 lds[NFFT];
    __shared__ float2 sh[NFFT/2];      // summed half-spectrum (packed elem 0)
    const int tid = threadIdx.x;
    const int bid = blockIdx.x;        // j*BATCH + b
    const int b = bid & (BATCH - 1);
    const int j = bid >> 5;

    float2 a[8];
    #pragma unroll
    for (int k = 0; k < 8; ++k) a[k] = make_float2(0.f, 0.f);
    #pragma unroll
    for (int u = 0; u < 8; ++u) {
        const int4* row4 = (const int4*)(Ph + (size_t)((u*COUT + j)*BATCH + b) * (NFFT/2));
        #pragma unroll
        for (int c = 0; c < 2; ++c) {
            const int4 w = row4[tid + 256*c];
            const int ww[4] = { w.x, w.y, w.z, w.w };
            #pragma unroll
            for (int r = 0; r < 4; ++r) {
                __half2 h = *(const __half2*)&ww[r];
                float2 f = __half22float2(h);
                a[c*4+r] = cadd(a[c*4+r], f);
            }
        }
    }
    float4* sh4 = (float4*)sh;
    #pragma unroll
    for (int c = 0; c < 2; ++c) {
        sh4[2*(tid + 256*c) + 0] = make_float4(a[c*4+0].x, a[c*4+0].y, a[c*4+1].x, a[c*4+1].y);
        sh4[2*(tid + 256*c) + 1] = make_float4(a[c*4+2].x, a[c*4+2].y, a[c*4+3].x, a[c*4+3].y);
    }
    __syncthreads();

    const float dc  = sh[0].x;
    const float nyq = sh[0].y;
    float2 v[16];
    #pragma unroll
    for (int k = 0; k < 8; ++k) v[k] = sh[tid + 256*k];
    if (tid == 0) v[0] = make_float2(dc, 0.0f);
    #pragma unroll
    for (int k = 8; k < 16; ++k) {
        const int m = 4096 - (tid + 256*k);          // mirror index in [1,2048]
        if (m == 2048) {                              // only tid==0, k==8
            v[k] = make_float2(nyq, 0.0f);
        } else {
            float2 c = sh[m];
            v[k] = make_float2(c.x, -c.y);            // conj
        }
    }
    // no barrier needed: fft writes lds[], sh[] untouched
    fft4096_r16<1>(v, lds, tid);
    const float invn = 1.0f / (float)NFFT;
    float* orow = out + (size_t)bid * NFFT;
    #pragma unroll
    for (int k = 0; k < 16; ++k) orow[tid + 256*k] = v[k].x * invn;
}

extern "C" void kernel_launch(void* const* d_in, const int* in_sizes, int n_in,
                              void* d_out, int out_size, void* d_ws, size_t ws_size,
                              hipStream_t stream) {
    const float* x = (const float*)d_in[0];   // (CIN, B, N)
    const float* G = (const float*)d_in[1];   // (CIN, COUT, R, N)
    const float* H = (const float*)d_in[2];   // (CIN, COUT, R, N)
    float* out = (float*)d_out;               // (COUT, B, N)

    float2*  Hc = (float2*)d_ws;                    // 32 packed pair rows (1 MB)
    float2*  Gf = Hc + (size_t)32 * NFFT;           // 64 rows (2 MB)
    float2*  Xf = Gf + (size_t)64 * NFFT;           // 128 rows (4 MB)
    __half2* Ph = (__half2*)(Xf + (size_t)128 * NFFT); // 1024 half-rows x 2048 h2 (8 MB)

    ldr_pre_k<<<224, NT, 0, stream>>>(x, G, H, Hc, Gf, Xf);
    ldr_mid_k<<<CIN * COUT * RANK * BATCH / 2, NT, 0, stream>>>(Hc, Xf, Gf, Ph);
    ldr_fin_k<<<COUT * BATCH, NT, 0, stream>>>(Ph, out);
}